// Round 12
// baseline (495.615 us; speedup 1.0000x reference)
//
#include <hip/hip_runtime.h>
#include <stdint.h>

#define B_ 4
#define S_ 2048
#define D_ 256
#define NH_ 12
#define M_ (B_*S_)      // 8192 rows of flattened input
#define J_ (NH_*D_)     // 3072 projection cols

typedef __bf16 bf16;
typedef __bf16 bf16x8 __attribute__((ext_vector_type(8)));
typedef __bf16 bf16x4 __attribute__((ext_vector_type(4)));
typedef float  f32x4  __attribute__((ext_vector_type(4)));

#define MFMA16(a,b,c) __builtin_amdgcn_mfma_f32_16x16x32_bf16(a,b,c,0,0,0)

__device__ __forceinline__ void g2lds16(void* l, const void* g) {
  __builtin_amdgcn_global_load_lds(
      (const __attribute__((address_space(1))) unsigned int*)g,
      (__attribute__((address_space(3))) unsigned int*)l, 16, 0, 0);
}

// ---------------- X fp32 -> bf16 ----------------
__global__ __launch_bounds__(256) void cvt_x(const float* __restrict__ in,
                                             bf16* __restrict__ out) {
  int i = blockIdx.x * 256 + threadIdx.x;
  f32x4 v = *(const f32x4*)(in + (size_t)i * 4);
  bf16x4 o;
#pragma unroll
  for (int k = 0; k < 4; ++k) o[k] = (bf16)v[k];
  *(bf16x4*)(out + (size_t)i * 4) = o;
}

// ------- weight transpose+cvt (both weights in one launch via blockIdx.z) -------
__global__ __launch_bounds__(256) void transpose_w(const float* __restrict__ W0,
                                                   bf16* __restrict__ T0,
                                                   const float* __restrict__ W1,
                                                   bf16* __restrict__ T1) {
  const float* W = blockIdx.z ? W1 : W0;
  bf16* Wt       = blockIdx.z ? T1 : T0;
  int j  = blockIdx.x * 256 + threadIdx.x;   // 0..3071, coalesced reads over j
  int c0 = blockIdx.y * 16;
  bf16x8 v0, v1;
#pragma unroll
  for (int i = 0; i < 8; ++i) v0[i] = (bf16)W[(size_t)(c0 + i) * J_ + j];
#pragma unroll
  for (int i = 0; i < 8; ++i) v1[i] = (bf16)W[(size_t)(c0 + 8 + i) * J_ + j];
  *(bf16x8*)(Wt + (size_t)j * D_ + c0)     = v0;
  *(bf16x8*)(Wt + (size_t)j * D_ + c0 + 8) = v1;
}

// ---------------- mask tile flags: 1 if 64x64 tile is all ones ----------------
__global__ __launch_bounds__(256) void mask_flags_k(const int* __restrict__ mask,
                                                    int* __restrict__ flags) {
  int bx = blockIdx.x;                 // b*1024 + st*32 + ft
  int ft = bx & 31, st = (bx >> 5) & 31, b = bx >> 10;
  int t = threadIdx.x;
  const int4* mp4 = (const int4*)(mask + (size_t)b * S_ * S_ +
                                  (size_t)(st * 64 + (t >> 2)) * S_ + ft * 64 + (t & 3) * 16);
  bool ok = true;
#pragma unroll
  for (int i = 0; i < 4; ++i) {
    int4 v = mp4[i];
    ok &= (v.x == 1) & (v.y == 1) & (v.z == 1) & (v.w == 1);
  }
  __shared__ int flag;
  if (t == 0) flag = 1;
  __syncthreads();
  if (!ok) flag = 0;                   // benign race, all write 0
  __syncthreads();
  if (t == 0) flags[bx] = flag;
}

// ---------------- GEMM body: C[M][N] = A[M][256] * Bm[N][256]^T + bias ----------
// 128x128 tile, BK=64, 4 waves each 64x64. XOR 8-chunk swizzle -> 2-way banks.
__device__ __forceinline__ void gemm_body(
    const bf16* __restrict__ A, const bf16* __restrict__ Bm,
    const float* __restrict__ bias, bf16* __restrict__ C,
    int Ndim, int bias_mode, int bid)
{
  __shared__ bf16 As[128 * 64];
  __shared__ bf16 Bs[128 * 64];
  const int nbn = Ndim >> 7;
  const int bm = bid / nbn, bn = bid % nbn;
  const int t = threadIdx.x, w = t >> 6, l = t & 63;
  const int lane16 = l & 15, quad = l >> 4;
  const int wm = (w & 1) << 6, wn = (w >> 1) << 6;
  const int srow = t >> 3;
  const int gc = (t & 7) ^ (srow & 7);
  const bf16* Ag = A + (size_t)((bm << 7) + srow) * 256 + gc * 8;
  const bf16* Bg = Bm + (size_t)((bn << 7) + srow) * 256 + gc * 8;
  f32x4 acc[4][4] = {};
  for (int k0 = 0; k0 < 256; k0 += 64) {
    __syncthreads();
#pragma unroll
    for (int i = 0; i < 4; ++i)
      g2lds16(As + (size_t)(i * 256 + (w << 6)) * 8, Ag + (size_t)i * 32 * 256 + k0);
#pragma unroll
    for (int i = 0; i < 4; ++i)
      g2lds16(Bs + (size_t)(i * 256 + (w << 6)) * 8, Bg + (size_t)i * 32 * 256 + k0);
    __syncthreads();
#pragma unroll
    for (int kt = 0; kt < 2; ++kt) {
      bf16x8 af[4], bfr[4];
#pragma unroll
      for (int i = 0; i < 4; ++i)
        af[i] = *(const bf16x8*)(As + (wm + i * 16 + lane16) * 64 +
                                 (((kt * 4 + quad) ^ (lane16 & 7)) * 8));
#pragma unroll
      for (int i = 0; i < 4; ++i)
        bfr[i] = *(const bf16x8*)(Bs + (wn + i * 16 + lane16) * 64 +
                                  (((kt * 4 + quad) ^ (lane16 & 7)) * 8));
#pragma unroll
      for (int i = 0; i < 4; ++i)
#pragma unroll
        for (int jx = 0; jx < 4; ++jx)
          acc[i][jx] = MFMA16(af[i], bfr[jx], acc[i][jx]);
    }
  }
#pragma unroll
  for (int i = 0; i < 4; ++i)
#pragma unroll
    for (int jx = 0; jx < 4; ++jx) {
      int col = (bn << 7) + wn + jx * 16 + lane16;
#pragma unroll
      for (int r = 0; r < 4; ++r) {
        int row = (bm << 7) + wm + i * 16 + quad * 4 + r;
        float v = acc[i][jx][r] + (bias_mode ? bias[row] : bias[col]);
        C[(size_t)row * Ndim + col] = (bf16)v;
      }
    }
}

// Both projections in ONE dispatch: blocks [0,1536) -> QK proj, [1536,3072) -> V^T proj.
__global__ __launch_bounds__(256) void gemm_both(
    const bf16* __restrict__ Xbf, const bf16* __restrict__ Wqkt,
    const float* __restrict__ bqk, bf16* __restrict__ QKw,
    const bf16* __restrict__ Wvt, const float* __restrict__ bv,
    bf16* __restrict__ Vtw)
{
  int bid = blockIdx.x;
  if (bid < 1536) gemm_body(Xbf, Wqkt, bqk, QKw, J_, 0, bid);
  else            gemm_body(Wvt, Xbf, bv, Vtw, M_, 1, bid - 1536);
}

// ---------------- fused attention (champion core, persistent grid) ----------------
// 512 blocks = exactly 2/CU, zero tail; block i processes tile i and (i<256) tile
// 512+i (XCD affinity preserved: 512%8==0). Core loop byte-identical to the 322us
// champion: transposed QK, wave-private P, K/V dbuf + 1-iter prefetch, 2 barriers.
// Registers pin occupancy at 2 blocks/CU — min-waves stays 2 (r9: 3 -> 86-reg spill).
__global__ __launch_bounds__(256, 2) void attn_k(
    const bf16* __restrict__ X, const bf16* __restrict__ QK, const bf16* __restrict__ Vt,
    const int* __restrict__ mask, const int* __restrict__ flags,
    float* __restrict__ Oacc)
{
  __shared__ bf16 Ks[2][32 * 256];
  __shared__ bf16 Vs[2][256 * 32];
  __shared__ bf16 Ps[4][32 * 40];
  const int t = threadIdx.x, w = t >> 6, l = t & 63;
  const int lane16 = l & 15, quad = l >> 4;

  for (int tile = blockIdx.x; tile < 768; tile += 512) {
    // XCD-aware decode: tile = xcd + 8*round; round = g_sub*16 + st; g = xcd + 8*g_sub
    const int x  = tile & 7, rr = tile >> 3;
    const int g  = x + 8 * (rr >> 4);            // 0..47 = b*12+n
    const int st = rr & 15;                      // 128-row s-tile
    const int b  = g / 12, n = g % 12;
    const int sw = (st << 7) + (w << 5);         // wave's first of 32 s-rows
    const bf16* Xb = X + (size_t)b * S_ * D_;
    bf16x8 qf[2][8];                             // Q frags (B operand): 2 s-tiles x 256 k
#pragma unroll
    for (int ts = 0; ts < 2; ++ts)
#pragma unroll
      for (int kt = 0; kt < 8; ++kt)
        qf[ts][kt] = *(const bf16x8*)(Xb + (size_t)(sw + ts * 16 + lane16) * D_ + kt * 32 + quad * 8);
    const bf16* QKb = QK + (size_t)b * S_ * J_ + n * D_;
    const bf16* Vtb = Vt + (size_t)n * D_ * M_ + (size_t)b * S_;
    const int* flagb = flags + (b * 32 + st * 2 + (w >> 1)) * 32;
    f32x4 oacc[2][16] = {};                      // O[32s][256d] (St orientation)
    float lsum[2] = {0.f, 0.f};                  // per-lane partial row sums (s=lane16)

    auto stage = [&](int buf, int f0) {
#pragma unroll
      for (int ii = 0; ii < 4; ++ii) {
        int frow = ii * 8 + (t >> 5);
        int dc = (t & 31) ^ (frow & 7);
        g2lds16(&Ks[buf][ii * 2048 + (w << 9)], QKb + (size_t)(f0 + frow) * J_ + dc * 8);
      }
#pragma unroll
      for (int ii = 0; ii < 4; ++ii) {
        int drow = ii * 64 + (t >> 2);
        int fc = (t & 3) ^ ((drow >> 1) & 3);
        g2lds16(&Vs[buf][ii * 2048 + (w << 9)], Vtb + (size_t)drow * M_ + f0 + fc * 8);
      }
    };

    stage(0, 0);                                 // prologue prefetch
    int cur = 0;
    for (int f0 = 0; f0 < S_; f0 += 32) {
      __syncthreads();     // drains DMA(cur) (issued a full iter ago); buf cur^1 free
      if (f0 + 32 < S_) stage(cur ^ 1, f0 + 32); // prefetch next tile under compute
      // St = K Q^T : C-layout col=lane16=s, row=quad*4+r=f.  A=kf, B=qf.
      f32x4 sfr[2][2] = {};                      // [ts][ct]
#pragma unroll
      for (int kt = 0; kt < 8; ++kt)
#pragma unroll
        for (int ct = 0; ct < 2; ++ct) {
          int fl = ct * 16 + lane16;             // A m-index rows f
          bf16x8 kf = *(const bf16x8*)(&Ks[cur][fl * 256 + (((kt * 4 + quad) ^ (fl & 7)) * 8)]);
          sfr[0][ct] = MFMA16(kf, qf[0][kt], sfr[0][ct]);
          sfr[1][ct] = MFMA16(kf, qf[1][kt], sfr[1][ct]);
        }
      // sfr[ts][ct][r] = S(s = sw+ts*16+lane16, f = f0+ct*16+quad*4+r)
      float ex[2][2][4];
      if (flagb[f0 >> 6]) {
#pragma unroll
        for (int ts = 0; ts < 2; ++ts)
#pragma unroll
          for (int ct = 0; ct < 2; ++ct)
#pragma unroll
            for (int r = 0; r < 4; ++r) ex[ts][ct][r] = __expf(sfr[ts][ct][r]);
      } else {
#pragma unroll
        for (int ts = 0; ts < 2; ++ts)
#pragma unroll
          for (int ct = 0; ct < 2; ++ct)
#pragma unroll
            for (int r = 0; r < 4; ++r) {
              int s = sw + ts * 16 + lane16, f = f0 + ct * 16 + quad * 4 + r;
              float add = (1.0f - (float)mask[(size_t)b * S_ * S_ + (size_t)s * S_ + f]) * -10000.0f;
              ex[ts][ct][r] = __expf(sfr[ts][ct][r] + add);
            }
      }
#pragma unroll
      for (int ts = 0; ts < 2; ++ts)
        lsum[ts] += ex[ts][0][0] + ex[ts][0][1] + ex[ts][0][2] + ex[ts][0][3]
                  + ex[ts][1][0] + ex[ts][1][1] + ex[ts][1][2] + ex[ts][1][3];
      // P -> wave-private LDS in A-operand orientation [s=row][f=col], 4 ds_write_b64
#pragma unroll
      for (int ts = 0; ts < 2; ++ts)
#pragma unroll
        for (int ct = 0; ct < 2; ++ct) {
          int base = (ts * 16 + lane16) * 40 + ct * 16 + quad * 4;
          bf16x4 pv;
          pv[0] = (bf16)ex[ts][ct][0]; pv[1] = (bf16)ex[ts][ct][1];
          pv[2] = (bf16)ex[ts][ct][2]; pv[3] = (bf16)ex[ts][ct][3];
          *(bf16x4*)(&Ps[w][base]) = pv;
        }
      // NO barrier: Ps region is wave-private; lgkmcnt ordering suffices.
      // O[32s][256d] += P * V  (A = P[s][f] from Ps, B = Vt[d][f])
      bf16x8 pf[2];
#pragma unroll
      for (int ts = 0; ts < 2; ++ts)
        pf[ts] = *(const bf16x8*)(&Ps[w][(ts * 16 + lane16) * 40 + quad * 8]);
#pragma unroll
      for (int dt = 0; dt < 16; ++dt) {
        int dl = dt * 16 + lane16;
        bf16x8 vf = *(const bf16x8*)(&Vs[cur][dl * 32 + ((quad ^ ((dl >> 1) & 3)) * 8)]);
        oacc[0][dt] = MFMA16(pf[0], vf, oacc[0][dt]);
        oacc[1][dt] = MFMA16(pf[1], vf, oacc[1][dt]);
      }
      cur ^= 1;
    }
    // finalize row sums: reduce across quads (lanes s, s+16, s+32, s+48)
    float tot[2];
#pragma unroll
    for (int ts = 0; ts < 2; ++ts) {
      float rs = lsum[ts];
      rs += __shfl_xor(rs, 16);
      rs += __shfl_xor(rs, 32);
      tot[ts] = rs;                              // every lane: total for s=ts*16+lane16
    }
    // normalize and head-sum into fp32 output: wave writes its 32 s x 256 d
    float* Ob = Oacc + (size_t)b * S_ * D_;
#pragma unroll
    for (int ts = 0; ts < 2; ++ts)
#pragma unroll
      for (int r = 0; r < 4; ++r) {
        float inv = 1.0f / __shfl(tot[ts], quad * 4 + r, 16);  // from lane16 = quad*4+r
        int s = sw + ts * 16 + quad * 4 + r;
#pragma unroll
        for (int dt = 0; dt < 16; ++dt) {
          int d = dt * 16 + lane16;
          unsafeAtomicAdd(&Ob[(size_t)s * D_ + d], oacc[ts][dt][r] * inv);
        }
      }
    if (tile + 512 < 768) __syncthreads();       // block reuses LDS for next tile
  }
}

extern "C" void kernel_launch(void* const* d_in, const int* in_sizes, int n_in,
                              void* d_out, int out_size, void* d_ws, size_t ws_size,
                              hipStream_t stream) {
  (void)in_sizes; (void)n_in; (void)out_size; (void)ws_size;
  const float* X    = (const float*)d_in[0];   // fp32 per reference
  const int*   mask = (const int*)d_in[1];
  const float* Wqk  = (const float*)d_in[2];
  const float* bqk  = (const float*)d_in[3];
  const float* Wv   = (const float*)d_in[4];
  const float* bv   = (const float*)d_in[5];
  float* out = (float*)d_out;                  // fp32 per reference output

  char* p = (char*)d_ws;
  bf16*  Xbf  = (bf16*)p;  p += (size_t)M_ * D_ * 2;      // 4.2 MB
  bf16*  Wqkt = (bf16*)p;  p += (size_t)J_ * D_ * 2;      // 1.5 MB
  bf16*  Wvt  = (bf16*)p;  p += (size_t)J_ * D_ * 2;      // 1.5 MB
  bf16*  QKw  = (bf16*)p;  p += (size_t)M_ * J_ * 2;      // 50.3 MB  [m][j]
  bf16*  Vtw  = (bf16*)p;  p += (size_t)J_ * M_ * 2;      // 50.3 MB  [j][m]
  int*   flags= (int*)p;   p += 4096 * 4;

  hipMemsetAsync(out, 0, (size_t)M_ * D_ * 4, stream);    // we accumulate into out
  cvt_x<<<(M_ * D_) / (256 * 4), 256, 0, stream>>>(X, Xbf);
  transpose_w<<<dim3(12, 16, 2), 256, 0, stream>>>(Wqk, Wqkt, Wv, Wvt);
  mask_flags_k<<<4096, 256, 0, stream>>>(mask, flags);
  gemm_both<<<3072, 256, 0, stream>>>(Xbf, Wqkt, bqk, QKw, Wvt, bv, Vtw);
  attn_k<<<512, 256, 0, stream>>>(Xbf, QKw, Vtw, mask, flags, out);
}

// Round 13
// 470.289 us; speedup vs baseline: 1.0539x; 1.0539x over previous
//
#include <hip/hip_runtime.h>
#include <stdint.h>

#define B_ 4
#define S_ 2048
#define D_ 256
#define NH_ 12
#define M_ (B_*S_)      // 8192 rows of flattened input
#define J_ (NH_*D_)     // 3072 projection cols

typedef __bf16 bf16;
typedef __bf16 bf16x8 __attribute__((ext_vector_type(8)));
typedef __bf16 bf16x4 __attribute__((ext_vector_type(4)));
typedef float  f32x4  __attribute__((ext_vector_type(4)));

#define MFMA16(a,b,c) __builtin_amdgcn_mfma_f32_16x16x32_bf16(a,b,c,0,0,0)

__device__ __forceinline__ void g2lds16(void* l, const void* g) {
  __builtin_amdgcn_global_load_lds(
      (const __attribute__((address_space(1))) unsigned int*)g,
      (__attribute__((address_space(3))) unsigned int*)l, 16, 0, 0);
}

// ---------------- X fp32 -> bf16 ----------------
__global__ __launch_bounds__(256) void cvt_x(const float* __restrict__ in,
                                             bf16* __restrict__ out) {
  int i = blockIdx.x * 256 + threadIdx.x;
  f32x4 v = *(const f32x4*)(in + (size_t)i * 4);
  bf16x4 o;
#pragma unroll
  for (int k = 0; k < 4; ++k) o[k] = (bf16)v[k];
  *(bf16x4*)(out + (size_t)i * 4) = o;
}

// ------- weight transpose+cvt (both weights in one launch via blockIdx.z) -------
__global__ __launch_bounds__(256) void transpose_w(const float* __restrict__ W0,
                                                   bf16* __restrict__ T0,
                                                   const float* __restrict__ W1,
                                                   bf16* __restrict__ T1) {
  const float* W = blockIdx.z ? W1 : W0;
  bf16* Wt       = blockIdx.z ? T1 : T0;
  int j  = blockIdx.x * 256 + threadIdx.x;   // 0..3071, coalesced reads over j
  int c0 = blockIdx.y * 16;
  bf16x8 v0, v1;
#pragma unroll
  for (int i = 0; i < 8; ++i) v0[i] = (bf16)W[(size_t)(c0 + i) * J_ + j];
#pragma unroll
  for (int i = 0; i < 8; ++i) v1[i] = (bf16)W[(size_t)(c0 + 8 + i) * J_ + j];
  *(bf16x8*)(Wt + (size_t)j * D_ + c0)     = v0;
  *(bf16x8*)(Wt + (size_t)j * D_ + c0 + 8) = v1;
}

// ---------------- mask tile flags: 1 if 64x64 tile is all ones ----------------
__global__ __launch_bounds__(256) void mask_flags_k(const int* __restrict__ mask,
                                                    int* __restrict__ flags) {
  int bx = blockIdx.x;                 // b*1024 + st*32 + ft
  int ft = bx & 31, st = (bx >> 5) & 31, b = bx >> 10;
  int t = threadIdx.x;
  const int4* mp4 = (const int4*)(mask + (size_t)b * S_ * S_ +
                                  (size_t)(st * 64 + (t >> 2)) * S_ + ft * 64 + (t & 3) * 16);
  bool ok = true;
#pragma unroll
  for (int i = 0; i < 4; ++i) {
    int4 v = mp4[i];
    ok &= (v.x == 1) & (v.y == 1) & (v.z == 1) & (v.w == 1);
  }
  __shared__ int flag;
  if (t == 0) flag = 1;
  __syncthreads();
  if (!ok) flag = 0;                   // benign race, all write 0
  __syncthreads();
  if (t == 0) flags[bx] = flag;
}

// ---------------- GEMM body: C[M][N] = A[M][256] * Bm[N][256]^T + bias ----------
// 128x128 tile, BK=64, 4 waves each 64x64. XOR 8-chunk swizzle -> 2-way banks.
__device__ __forceinline__ void gemm_body(
    const bf16* __restrict__ A, const bf16* __restrict__ Bm,
    const float* __restrict__ bias, bf16* __restrict__ C,
    int Ndim, int bias_mode, int bid)
{
  __shared__ bf16 As[128 * 64];
  __shared__ bf16 Bs[128 * 64];
  const int nbn = Ndim >> 7;
  const int bm = bid / nbn, bn = bid % nbn;
  const int t = threadIdx.x, w = t >> 6, l = t & 63;
  const int lane16 = l & 15, quad = l >> 4;
  const int wm = (w & 1) << 6, wn = (w >> 1) << 6;
  const int srow = t >> 3;
  const int gc = (t & 7) ^ (srow & 7);
  const bf16* Ag = A + (size_t)((bm << 7) + srow) * 256 + gc * 8;
  const bf16* Bg = Bm + (size_t)((bn << 7) + srow) * 256 + gc * 8;
  f32x4 acc[4][4] = {};
  for (int k0 = 0; k0 < 256; k0 += 64) {
    __syncthreads();
#pragma unroll
    for (int i = 0; i < 4; ++i)
      g2lds16(As + (size_t)(i * 256 + (w << 6)) * 8, Ag + (size_t)i * 32 * 256 + k0);
#pragma unroll
    for (int i = 0; i < 4; ++i)
      g2lds16(Bs + (size_t)(i * 256 + (w << 6)) * 8, Bg + (size_t)i * 32 * 256 + k0);
    __syncthreads();
#pragma unroll
    for (int kt = 0; kt < 2; ++kt) {
      bf16x8 af[4], bfr[4];
#pragma unroll
      for (int i = 0; i < 4; ++i)
        af[i] = *(const bf16x8*)(As + (wm + i * 16 + lane16) * 64 +
                                 (((kt * 4 + quad) ^ (lane16 & 7)) * 8));
#pragma unroll
      for (int i = 0; i < 4; ++i)
        bfr[i] = *(const bf16x8*)(Bs + (wn + i * 16 + lane16) * 64 +
                                  (((kt * 4 + quad) ^ (lane16 & 7)) * 8));
#pragma unroll
      for (int i = 0; i < 4; ++i)
#pragma unroll
        for (int jx = 0; jx < 4; ++jx)
          acc[i][jx] = MFMA16(af[i], bfr[jx], acc[i][jx]);
    }
  }
#pragma unroll
  for (int i = 0; i < 4; ++i)
#pragma unroll
    for (int jx = 0; jx < 4; ++jx) {
      int col = (bn << 7) + wn + jx * 16 + lane16;
#pragma unroll
      for (int r = 0; r < 4; ++r) {
        int row = (bm << 7) + wm + i * 16 + quad * 4 + r;
        float v = acc[i][jx][r] + (bias_mode ? bias[row] : bias[col]);
        C[(size_t)row * Ndim + col] = (bf16)v;
      }
    }
}

// Both projections in ONE dispatch: blocks [0,1536) -> QK proj, [1536,3072) -> V^T proj.
__global__ __launch_bounds__(256) void gemm_both(
    const bf16* __restrict__ Xbf, const bf16* __restrict__ Wqkt,
    const float* __restrict__ bqk, bf16* __restrict__ QKw,
    const bf16* __restrict__ Wvt, const float* __restrict__ bv,
    bf16* __restrict__ Vtw)
{
  int bid = blockIdx.x;
  if (bid < 1536) gemm_body(Xbf, Wqkt, bqk, QKw, J_, 0, bid);
  else            gemm_body(Wvt, Xbf, bv, Vtw, M_, 1, bid - 1536);
}

// ---------------- fused attention (322-333us champion, 768-block grid) ----------------
// XCD-swizzled grid. Block: 4 waves, 128 s-rows; wave owns 32 s-rows end-to-end.
// TRANSPOSED QK (A=K-frag, B=Q-frag) -> St C-layout col=lane16=s, row=quad*4+r=f.
// P: wave-private Ps[32][40], no barrier. K/V double-buffered, 1-iter prefetch.
// 2 barriers/iter. Registers pin occupancy at 2 blocks/CU — NEVER raise
// launch_bounds min-waves above 2 (r9: (256,3) -> 86-reg spill, 2GB scratch).
// NEVER make the grid persistent (r12: 512-block persistent -> +19MB fetch,
// +32MB write, 333->371us; natural dispatch order has better L2 timing).
__global__ __launch_bounds__(256, 2) void attn_k(
    const bf16* __restrict__ X, const bf16* __restrict__ QK, const bf16* __restrict__ Vt,
    const int* __restrict__ mask, const int* __restrict__ flags,
    float* __restrict__ Oacc)
{
  __shared__ bf16 Ks[2][32 * 256];
  __shared__ bf16 Vs[2][256 * 32];
  __shared__ bf16 Ps[4][32 * 40];
  // XCD-aware remap: i = xcd + 8*round; round = g_sub*16 + st; group g = xcd + 8*g_sub
  const int i  = blockIdx.x;
  const int x  = i & 7, rr = i >> 3;
  const int g  = x + 8 * (rr >> 4);            // 0..47 = b*12+n
  const int st = rr & 15;                      // 128-row s-tile
  const int b  = g / 12, n = g % 12;
  const int t = threadIdx.x, w = t >> 6, l = t & 63;
  const int lane16 = l & 15, quad = l >> 4;
  const int sw = (st << 7) + (w << 5);          // wave's first of 32 s-rows
  const bf16* Xb = X + (size_t)b * S_ * D_;
  bf16x8 qf[2][8];                              // Q frags (B operand): 2 s-tiles x 256 k
#pragma unroll
  for (int ts = 0; ts < 2; ++ts)
#pragma unroll
    for (int kt = 0; kt < 8; ++kt)
      qf[ts][kt] = *(const bf16x8*)(Xb + (size_t)(sw + ts * 16 + lane16) * D_ + kt * 32 + quad * 8);
  const bf16* QKb = QK + (size_t)b * S_ * J_ + n * D_;
  const bf16* Vtb = Vt + (size_t)n * D_ * M_ + (size_t)b * S_;
  // flags row for this wave's 64-row tile: st*2 + (w>>1)
  const int* flagb = flags + (b * 32 + st * 2 + (w >> 1)) * 32;
  f32x4 oacc[2][16] = {};                       // O[32s][256d] (St orientation)
  float lsum[2] = {0.f, 0.f};                   // per-lane partial row sums (s=lane16)

  // staging helper: loads f-tile f0 into buffer `buf`
  auto stage = [&](int buf, int f0) {
#pragma unroll
    for (int ii = 0; ii < 4; ++ii) {
      int frow = ii * 8 + (t >> 5);
      int dc = (t & 31) ^ (frow & 7);
      g2lds16(&Ks[buf][ii * 2048 + (w << 9)], QKb + (size_t)(f0 + frow) * J_ + dc * 8);
    }
#pragma unroll
    for (int ii = 0; ii < 4; ++ii) {
      int drow = ii * 64 + (t >> 2);
      int fc = (t & 3) ^ ((drow >> 1) & 3);
      g2lds16(&Vs[buf][ii * 2048 + (w << 9)], Vtb + (size_t)drow * M_ + f0 + fc * 8);
    }
  };

  stage(0, 0);                                  // prologue prefetch
  int cur = 0;
  for (int f0 = 0; f0 < S_; f0 += 32) {
    __syncthreads();       // drains DMA(cur) (issued a full iter ago); buf cur^1 free
    if (f0 + 32 < S_) stage(cur ^ 1, f0 + 32);  // prefetch next tile under compute
    // St = K Q^T : C-layout col=lane16=s, row=quad*4+r=f.  A=kf, B=qf.
    f32x4 sfr[2][2] = {};                       // [ts][ct]
#pragma unroll
    for (int kt = 0; kt < 8; ++kt)
#pragma unroll
      for (int ct = 0; ct < 2; ++ct) {
        int fl = ct * 16 + lane16;              // A m-index rows f
        bf16x8 kf = *(const bf16x8*)(&Ks[cur][fl * 256 + (((kt * 4 + quad) ^ (fl & 7)) * 8)]);
        sfr[0][ct] = MFMA16(kf, qf[0][kt], sfr[0][ct]);
        sfr[1][ct] = MFMA16(kf, qf[1][kt], sfr[1][ct]);
      }
    // sfr[ts][ct][r] = S(s = sw+ts*16+lane16, f = f0+ct*16+quad*4+r)
    float ex[2][2][4];
    if (flagb[f0 >> 6]) {
#pragma unroll
      for (int ts = 0; ts < 2; ++ts)
#pragma unroll
        for (int ct = 0; ct < 2; ++ct)
#pragma unroll
          for (int r = 0; r < 4; ++r) ex[ts][ct][r] = __expf(sfr[ts][ct][r]);
    } else {
#pragma unroll
      for (int ts = 0; ts < 2; ++ts)
#pragma unroll
        for (int ct = 0; ct < 2; ++ct)
#pragma unroll
          for (int r = 0; r < 4; ++r) {
            int s = sw + ts * 16 + lane16, f = f0 + ct * 16 + quad * 4 + r;
            float add = (1.0f - (float)mask[(size_t)b * S_ * S_ + (size_t)s * S_ + f]) * -10000.0f;
            ex[ts][ct][r] = __expf(sfr[ts][ct][r] + add);
          }
    }
#pragma unroll
    for (int ts = 0; ts < 2; ++ts)
      lsum[ts] += ex[ts][0][0] + ex[ts][0][1] + ex[ts][0][2] + ex[ts][0][3]
                + ex[ts][1][0] + ex[ts][1][1] + ex[ts][1][2] + ex[ts][1][3];
    // P -> wave-private LDS in A-operand orientation [s=row][f=col], 4 ds_write_b64
#pragma unroll
    for (int ts = 0; ts < 2; ++ts)
#pragma unroll
      for (int ct = 0; ct < 2; ++ct) {
        int base = (ts * 16 + lane16) * 40 + ct * 16 + quad * 4;
        bf16x4 pv;
        pv[0] = (bf16)ex[ts][ct][0]; pv[1] = (bf16)ex[ts][ct][1];
        pv[2] = (bf16)ex[ts][ct][2]; pv[3] = (bf16)ex[ts][ct][3];
        *(bf16x4*)(&Ps[w][base]) = pv;
      }
    // NO barrier: Ps region is wave-private; lgkmcnt ordering suffices.
    // O[32s][256d] += P * V  (A = P[s][f] from Ps, B = Vt[d][f])
    bf16x8 pf[2];
#pragma unroll
    for (int ts = 0; ts < 2; ++ts)
      pf[ts] = *(const bf16x8*)(&Ps[w][(ts * 16 + lane16) * 40 + quad * 8]);
#pragma unroll
    for (int dt = 0; dt < 16; ++dt) {
      int dl = dt * 16 + lane16;
      bf16x8 vf = *(const bf16x8*)(&Vs[cur][dl * 32 + ((quad ^ ((dl >> 1) & 3)) * 8)]);
      oacc[0][dt] = MFMA16(pf[0], vf, oacc[0][dt]);
      oacc[1][dt] = MFMA16(pf[1], vf, oacc[1][dt]);
    }
    cur ^= 1;
  }
  // finalize row sums: reduce across quads (lanes s, s+16, s+32, s+48)
  float tot[2];
#pragma unroll
  for (int ts = 0; ts < 2; ++ts) {
    float rs = lsum[ts];
    rs += __shfl_xor(rs, 16);
    rs += __shfl_xor(rs, 32);
    tot[ts] = rs;                               // every lane: total for s=ts*16+lane16
  }
  // normalize and head-sum into fp32 output: wave writes its 32 s x 256 d
  float* Ob = Oacc + (size_t)b * S_ * D_;
#pragma unroll
  for (int ts = 0; ts < 2; ++ts)
#pragma unroll
    for (int r = 0; r < 4; ++r) {
      float inv = 1.0f / __shfl(tot[ts], quad * 4 + r, 16);  // from lane16 = quad*4+r
      int s = sw + ts * 16 + quad * 4 + r;
#pragma unroll
      for (int dt = 0; dt < 16; ++dt) {
        int d = dt * 16 + lane16;
        unsafeAtomicAdd(&Ob[(size_t)s * D_ + d], oacc[ts][dt][r] * inv);
      }
    }
}

extern "C" void kernel_launch(void* const* d_in, const int* in_sizes, int n_in,
                              void* d_out, int out_size, void* d_ws, size_t ws_size,
                              hipStream_t stream) {
  (void)in_sizes; (void)n_in; (void)out_size; (void)ws_size;
  const float* X    = (const float*)d_in[0];   // fp32 per reference
  const int*   mask = (const int*)d_in[1];
  const float* Wqk  = (const float*)d_in[2];
  const float* bqk  = (const float*)d_in[3];
  const float* Wv   = (const float*)d_in[4];
  const float* bv   = (const float*)d_in[5];
  float* out = (float*)d_out;                  // fp32 per reference output

  char* p = (char*)d_ws;
  bf16*  Xbf  = (bf16*)p;  p += (size_t)M_ * D_ * 2;      // 4.2 MB
  bf16*  Wqkt = (bf16*)p;  p += (size_t)J_ * D_ * 2;      // 1.5 MB
  bf16*  Wvt  = (bf16*)p;  p += (size_t)J_ * D_ * 2;      // 1.5 MB
  bf16*  QKw  = (bf16*)p;  p += (size_t)M_ * J_ * 2;      // 50.3 MB  [m][j]
  bf16*  Vtw  = (bf16*)p;  p += (size_t)J_ * M_ * 2;      // 50.3 MB  [j][m]
  int*   flags= (int*)p;   p += 4096 * 4;

  hipMemsetAsync(out, 0, (size_t)M_ * D_ * 4, stream);    // we accumulate into out
  cvt_x<<<(M_ * D_) / (256 * 4), 256, 0, stream>>>(X, Xbf);
  transpose_w<<<dim3(12, 16, 2), 256, 0, stream>>>(Wqk, Wqkt, Wv, Wvt);
  mask_flags_k<<<4096, 256, 0, stream>>>(mask, flags);
  gemm_both<<<3072, 256, 0, stream>>>(Xbf, Wqkt, bqk, QKw, Wvt, bv, Vtw);
  attn_k<<<B_ * NH_ * (S_ / 128), 256, 0, stream>>>(Xbf, QKw, Vtw, mask, flags, out);
}